// Round 4
// baseline (462.740 us; speedup 1.0000x reference)
//
#include <hip/hip_runtime.h>

#define NB 32
#define NF 256
#define NT 4096
#define PAD_LEN 256

#define TF 16
#define TT 128

// f32 gaussian weights: exp(-0.5*c^2)/sum, c=-2..2, sigma=1
#define G0 0.054488684f
#define G1 0.24420134f
#define G2 0.40261995f

// All LDS arrays share column indexing: slot s <-> global col t0-4+s, s in [0,136)
// Row stride 136 floats (544B, 16B-aligned rows).
#define SW 136
#define SW4 34
#define RS 24   // sS rows: global f0-4 .. f0+19
#define RP 22   // sP rows: global f0-3 .. f0+18
#define RV 18   // sV/sB rows: global f0-1 .. f0+16

#define R1_WORDS (RS * SW)  // sS, overlaid by sV
#define R2_WORDS (RP * SW)  // sP, overlaid by sB

__device__ __forceinline__ int reflectF(int i) {
    i = (i < 0) ? -i : i;
    return (i >= NF) ? (2 * NF - 2 - i) : i;
}
__device__ __forceinline__ int reflectT(int i) {
    i = (i < 0) ? -i : i;
    return (i >= NT) ? (2 * NT - 2 - i) : i;
}
// order-preserving float->uint encoding for atomicMin/Max
__device__ __forceinline__ unsigned encf(float x) {
    unsigned u = __float_as_uint(x);
    return (u & 0x80000000u) ? ~u : (u | 0x80000000u);
}
__device__ __forceinline__ float decf(unsigned e) {
    unsigned u = (e & 0x80000000u) ? (e ^ 0x80000000u) : ~e;
    return __uint_as_float(u);
}

// async global->LDS 16B DMA (per-lane gather, wave-uniform LDS base + lane*16)
__device__ __forceinline__ void gload_lds16(const float4* gsrc, float4* ldst) {
    __builtin_amdgcn_global_load_lds((const __attribute__((address_space(1))) void*)(const void*)gsrc,
                                     (__attribute__((address_space(3))) void*)(void*)ldst, 16, 0, 0);
}

// ws layout: mm[NB][4] @0 ; counts2[NB][NF][32] @1024 ; prefix2 @1024+1MB
#define MM_OFF 0
#define CNT_OFF 1024
#define PFX_OFF (1024 + NB * NF * 32 * 4)

__global__ __launch_bounds__(256) void k_init(float* __restrict__ out, unsigned* __restrict__ mm) {
    int tid = blockIdx.x * 256 + threadIdx.x;
    if (tid < NB * 3 * PAD_LEN) out[tid] = 0.0f;
    if (tid < NB) {
        mm[tid * 4 + 0] = 0xFFFFFFFFu;
        mm[tid * 4 + 1] = 0u;
        mm[tid * 4 + 2] = 0xFFFFFFFFu;
        mm[tid * 4 + 3] = 0u;
    }
}

__global__ __launch_bounds__(256) void k_minmax(const float* __restrict__ spec, unsigned* __restrict__ mm) {
    const int b = blockIdx.y;
    const float4* p = (const float4*)(spec + (size_t)b * NF * NT);
    const int base4 = blockIdx.x * 4096;
    float lmin = __builtin_inff(), lmax = -__builtin_inff();
    for (int i = threadIdx.x; i < 4096; i += 256) {
        float4 v = p[base4 + i];
        lmin = fminf(lmin, fminf(fminf(v.x, v.y), fminf(v.z, v.w)));
        lmax = fmaxf(lmax, fmaxf(fmaxf(v.x, v.y), fmaxf(v.z, v.w)));
    }
    for (int off = 32; off; off >>= 1) {
        lmin = fminf(lmin, __shfl_down(lmin, off));
        lmax = fmaxf(lmax, __shfl_down(lmax, off));
    }
    __shared__ float rmn[4], rmx[4];
    int wave = threadIdx.x >> 6, lane = threadIdx.x & 63;
    if (lane == 0) { rmn[wave] = lmin; rmx[wave] = lmax; }
    __syncthreads();
    if (threadIdx.x == 0) {
        for (int w = 1; w < 4; w++) { lmin = fminf(lmin, rmn[w]); lmax = fmaxf(lmax, rmx[w]); }
        atomicMin(&mm[b * 4 + 0], encf(lmin));
        atomicMax(&mm[b * 4 + 1], encf(lmax));
    }
}

// ---------- interior (fast) tile: ILP-unrolled, paired items, DMA staging ----------
__device__ __forceinline__ void blur_tile_fast(const float* __restrict__ sb_base,
                                               int f0, int t0, float mn, float rinv,
                                               float* sR1, float* sR2, int tid) {
    float4* sS4 = (float4*)sR1;
    float4* sP4 = (float4*)sR2;
    float4* sV4 = (float4*)sR1;  // overlays sS
    float4* sB4 = (float4*)sR2;  // overlays sP
    float* sS = sR1;
    float* sV = sR1;
    float* sB = sR2;

    // Phase A: DMA spec rows f0-4..f0+19, slots 0..135
    {
        const float4* gp = (const float4*)(sb_base + (size_t)(f0 - 4) * NT + (t0 - 4));
#pragma unroll
        for (int k = 0; k < 4; k++) {
            const int i = tid + k * 256;
            if (i < RS * SW4) {
                const int r = i / SW4, c = i - r * SW4;
                gload_lds16(gp + r * (NT / 4) + c, sS4 + i);
            }
        }
    }
    __syncthreads();

    // Phase B: peak(spec)*norm -> sP, row-pairs (11 pairs x 34 col-groups = 374 items)
    {
        float4 S0[2], S1[2], S2[2], S3[2];
        float lmA[2], rpA[2], lmB[2], rpB[2];
        int r0a[2], ga[2];
        bool act[2];
#pragma unroll
        for (int k = 0; k < 2; k++) {
            const int i = tid + k * 256;
            act[k] = i < 11 * SW4;
            if (act[k]) {
                const int pr = i / SW4, g = i - pr * SW4;
                const int r0 = 2 * pr;
                r0a[k] = r0; ga[k] = g;
                S0[k] = sS4[r0 * SW4 + g];
                S1[k] = sS4[(r0 + 1) * SW4 + g];
                S2[k] = sS4[(r0 + 2) * SW4 + g];
                S3[k] = sS4[(r0 + 3) * SW4 + g];
                lmA[k] = sS[(r0 + 1) * SW + 4 * g - 1];
                rpA[k] = sS[(r0 + 1) * SW + 4 * g + 4];
                lmB[k] = sS[(r0 + 2) * SW + 4 * g - 1];
                rpB[k] = sS[(r0 + 2) * SW + 4 * g + 4];
            }
        }
#pragma unroll
        for (int k = 0; k < 2; k++) {
            if (act[k]) {
                const int g = ga[k], r0 = r0a[k];
                float4 o, p;
                // row A: up S0, center S1, down S2
                o.x = (S1[k].x >= lmA[k] && S1[k].x >= S1[k].y && S1[k].x >= S0[k].x && S1[k].x >= S2[k].x) ? (S1[k].x - mn) * rinv : 0.0f;
                o.y = (S1[k].y >= S1[k].x && S1[k].y >= S1[k].z && S1[k].y >= S0[k].y && S1[k].y >= S2[k].y) ? (S1[k].y - mn) * rinv : 0.0f;
                o.z = (S1[k].z >= S1[k].y && S1[k].z >= S1[k].w && S1[k].z >= S0[k].z && S1[k].z >= S2[k].z) ? (S1[k].z - mn) * rinv : 0.0f;
                o.w = (S1[k].w >= S1[k].z && S1[k].w >= rpA[k] && S1[k].w >= S0[k].w && S1[k].w >= S2[k].w) ? (S1[k].w - mn) * rinv : 0.0f;
                // row B: up S1, center S2, down S3
                p.x = (S2[k].x >= lmB[k] && S2[k].x >= S2[k].y && S2[k].x >= S1[k].x && S2[k].x >= S3[k].x) ? (S2[k].x - mn) * rinv : 0.0f;
                p.y = (S2[k].y >= S2[k].x && S2[k].y >= S2[k].z && S2[k].y >= S1[k].y && S2[k].y >= S3[k].y) ? (S2[k].y - mn) * rinv : 0.0f;
                p.z = (S2[k].z >= S2[k].y && S2[k].z >= S2[k].w && S2[k].z >= S1[k].z && S2[k].z >= S3[k].z) ? (S2[k].z - mn) * rinv : 0.0f;
                p.w = (S2[k].w >= S2[k].z && S2[k].w >= rpB[k] && S2[k].w >= S1[k].w && S2[k].w >= S3[k].w) ? (S2[k].w - mn) * rinv : 0.0f;
                if (g == 0)  { o.x = 0.0f; p.x = 0.0f; }
                if (g == 33) { o.w = 0.0f; p.w = 0.0f; }
                sP4[r0 * SW4 + g] = o;
                sP4[(r0 + 1) * SW4 + g] = p;
            }
        }
    }
    __syncthreads();

    // Phase C: vertical 5-tap -> sV, row-pairs (9 pairs x 34 = 306 items)
    {
        float4 P[2][6];
        int idx[2];
        bool act[2];
#pragma unroll
        for (int k = 0; k < 2; k++) {
            const int i = tid + k * 256;
            act[k] = i < 9 * SW4;
            if (act[k]) {
                const int pv = i / SW4, g = i - pv * SW4;
                const int r0 = 2 * pv;
                idx[k] = r0 * SW4 + g;
#pragma unroll
                for (int j = 0; j < 6; j++) P[k][j] = sP4[(r0 + j) * SW4 + g];
            }
        }
#pragma unroll
        for (int k = 0; k < 2; k++) {
            if (act[k]) {
                float4 a, b;
                a.x = G0 * (P[k][0].x + P[k][4].x) + G1 * (P[k][1].x + P[k][3].x) + G2 * P[k][2].x;
                a.y = G0 * (P[k][0].y + P[k][4].y) + G1 * (P[k][1].y + P[k][3].y) + G2 * P[k][2].y;
                a.z = G0 * (P[k][0].z + P[k][4].z) + G1 * (P[k][1].z + P[k][3].z) + G2 * P[k][2].z;
                a.w = G0 * (P[k][0].w + P[k][4].w) + G1 * (P[k][1].w + P[k][3].w) + G2 * P[k][2].w;
                b.x = G0 * (P[k][1].x + P[k][5].x) + G1 * (P[k][2].x + P[k][4].x) + G2 * P[k][3].x;
                b.y = G0 * (P[k][1].y + P[k][5].y) + G1 * (P[k][2].y + P[k][4].y) + G2 * P[k][3].y;
                b.z = G0 * (P[k][1].z + P[k][5].z) + G1 * (P[k][2].z + P[k][4].z) + G2 * P[k][3].z;
                b.w = G0 * (P[k][1].w + P[k][5].w) + G1 * (P[k][2].w + P[k][4].w) + G2 * P[k][3].w;
                sV4[idx[k]] = a;
                sV4[idx[k] + SW4] = b;
            }
        }
    }
    __syncthreads();

    // Phase D: horizontal 5-tap -> sB, col-pairs (18 rows x 16 = 288 items) + 36 edges
    {
        float4 VA[2], VB[2], VC[2], VD[2];
        int od[2];
        bool act[2];
#pragma unroll
        for (int k = 0; k < 2; k++) {
            const int i = tid + k * 256;
            act[k] = i < RV * 16;
            if (act[k]) {
                const int r = i >> 4, m = i & 15;
                const int g = 1 + 2 * m;
                od[k] = r * SW4 + g;
                VA[k] = sV4[r * SW4 + g - 1];
                VB[k] = sV4[r * SW4 + g];
                VC[k] = sV4[r * SW4 + g + 1];
                VD[k] = sV4[r * SW4 + g + 2];
            }
        }
        float ev[5];
        int eidx = 0;
        const bool eact = tid < RV * 2;
        if (eact) {
            const int r = tid >> 1;
            const int s = (tid & 1) ? 132 : 3;
            eidx = r * SW + s;
#pragma unroll
            for (int j = 0; j < 5; j++) ev[j] = sV[eidx - 2 + j];
        }
#pragma unroll
        for (int k = 0; k < 2; k++) {
            if (act[k]) {
                float4 o1, o2;
                o1.x = G0 * (VA[k].z + VB[k].z) + G1 * (VA[k].w + VB[k].y) + G2 * VB[k].x;
                o1.y = G0 * (VA[k].w + VB[k].w) + G1 * (VB[k].x + VB[k].z) + G2 * VB[k].y;
                o1.z = G0 * (VB[k].x + VC[k].x) + G1 * (VB[k].y + VB[k].w) + G2 * VB[k].z;
                o1.w = G0 * (VB[k].y + VC[k].y) + G1 * (VB[k].z + VC[k].x) + G2 * VB[k].w;
                o2.x = G0 * (VB[k].z + VC[k].z) + G1 * (VB[k].w + VC[k].y) + G2 * VC[k].x;
                o2.y = G0 * (VB[k].w + VC[k].w) + G1 * (VC[k].x + VC[k].z) + G2 * VC[k].y;
                o2.z = G0 * (VC[k].x + VD[k].x) + G1 * (VC[k].y + VC[k].w) + G2 * VC[k].z;
                o2.w = G0 * (VC[k].y + VD[k].y) + G1 * (VC[k].z + VD[k].x) + G2 * VC[k].w;
                sB4[od[k]] = o1;
                sB4[od[k] + 1] = o2;
            }
        }
        if (eact) sB[eidx] = G0 * (ev[0] + ev[4]) + G1 * (ev[1] + ev[3]) + G2 * ev[2];
    }
    __syncthreads();
}

// ---------- boundary (slow) tile: guarded, reflect-indexed ----------
__device__ __forceinline__ void blur_tile_slow(const float* __restrict__ sb_base,
                                               int f0, int t0, float mn, float rinv,
                                               float* sR1, float* sR2, int tid) {
    const float NEG = -__builtin_inff();
    float* sS = sR1;
    float* sP = sR2;
    float* sV = sR1;
    float* sB = sR2;

    for (int i = tid; i < RS * SW; i += 256) {
        int r = i / SW, c = i - r * SW;
        int gf = f0 - 4 + r, gc = t0 - 4 + c;
        float v = NEG;
        if ((unsigned)gf < NF && (unsigned)gc < NT) v = sb_base[gf * NT + gc];
        sS[i] = v;
    }
    __syncthreads();

    for (int i = tid; i < RP * 134; i += 256) {
        int r = i / 134, s = 1 + (i - r * 134);
        int gf = f0 - 3 + r, gc = t0 - 4 + s;
        float v = 0.0f;
        if ((unsigned)gf < NF && (unsigned)gc < NT) {
            const float x  = sS[(r + 1) * SW + s];
            const float xl = sS[(r + 1) * SW + s - 1];
            const float xr = sS[(r + 1) * SW + s + 1];
            const float xu = sS[r * SW + s];
            const float xd = sS[(r + 2) * SW + s];
            if (x >= xl && x >= xr && x >= xu && x >= xd) v = (x - mn) * rinv;
        }
        sP[r * SW + s] = v;
    }
    __syncthreads();

    for (int i = tid; i < RV * 134; i += 256) {
        int r = i / 134, s = 1 + (i - r * 134);
        int gf = f0 - 1 + r, gc = t0 - 4 + s;
        float acc = 0.0f;
        if ((unsigned)gf < NF && (unsigned)gc < NT) {
            int rm2 = reflectF(gf - 2) - (f0 - 3);
            int rm1 = reflectF(gf - 1) - (f0 - 3);
            int rcc = gf - (f0 - 3);
            int rp1 = reflectF(gf + 1) - (f0 - 3);
            int rp2 = reflectF(gf + 2) - (f0 - 3);
            acc  = G0 * sP[rm2 * SW + s];
            acc += G1 * sP[rm1 * SW + s];
            acc += G2 * sP[rcc * SW + s];
            acc += G1 * sP[rp1 * SW + s];
            acc += G0 * sP[rp2 * SW + s];
        }
        sV[r * SW + s] = acc;
    }
    __syncthreads();

    for (int i = tid; i < RV * 130; i += 256) {
        int r = i / 130, s = 3 + (i - r * 130);
        int gf = f0 - 1 + r, gc = t0 - 4 + s;
        float acc = NEG;
        if ((unsigned)gf < NF && (unsigned)gc < NT) {
            int cm2 = reflectT(gc - 2) - (t0 - 4);
            int cm1 = reflectT(gc - 1) - (t0 - 4);
            int cp1 = reflectT(gc + 1) - (t0 - 4);
            int cp2 = reflectT(gc + 2) - (t0 - 4);
            const float* vr = sV + r * SW;
            acc  = G0 * (vr[cm2] + vr[cp2]);
            acc += G1 * (vr[cm1] + vr[cp1]);
            acc += G2 * vr[s];
        }
        sB[r * SW + s] = acc;
    }
    __syncthreads();
}

// Epilogue helper: 8-col window for row r (global f0+r), octet m (cols t0+8m..+7)
struct Win8 {
    float c[8], l[8], rr[8], u[8], d[8];
};
__device__ __forceinline__ void load_win8(const float4* sB4, int r, int m, Win8& w) {
    const int g = 1 + 2 * m;
    const float4 Cm = sB4[(r + 1) * SW4 + g - 1];
    const float4 C0 = sB4[(r + 1) * SW4 + g];
    const float4 C1 = sB4[(r + 1) * SW4 + g + 1];
    const float4 C2 = sB4[(r + 1) * SW4 + g + 2];
    const float4 U0 = sB4[r * SW4 + g];
    const float4 U1 = sB4[r * SW4 + g + 1];
    const float4 D0 = sB4[(r + 2) * SW4 + g];
    const float4 D1 = sB4[(r + 2) * SW4 + g + 1];
    w.c[0] = C0.x; w.c[1] = C0.y; w.c[2] = C0.z; w.c[3] = C0.w;
    w.c[4] = C1.x; w.c[5] = C1.y; w.c[6] = C1.z; w.c[7] = C1.w;
    w.l[0] = Cm.w; w.l[1] = C0.x; w.l[2] = C0.y; w.l[3] = C0.z;
    w.l[4] = C0.w; w.l[5] = C1.x; w.l[6] = C1.y; w.l[7] = C1.z;
    w.rr[0] = C0.y; w.rr[1] = C0.z; w.rr[2] = C0.w; w.rr[3] = C1.x;
    w.rr[4] = C1.y; w.rr[5] = C1.z; w.rr[6] = C1.w; w.rr[7] = C2.x;
    w.u[0] = U0.x; w.u[1] = U0.y; w.u[2] = U0.z; w.u[3] = U0.w;
    w.u[4] = U1.x; w.u[5] = U1.y; w.u[6] = U1.z; w.u[7] = U1.w;
    w.d[0] = D0.x; w.d[1] = D0.y; w.d[2] = D0.z; w.d[3] = D0.w;
    w.d[4] = D1.x; w.d[5] = D1.y; w.d[6] = D1.z; w.d[7] = D1.w;
}

// Main pass: blur + blur-min/max + per-(row,chunk) counts with threshold x > 0
// (valid when mn2 == 0, which holds because blur >= 0 and empty 5x5 windows exist;
//  k_fallback recounts with the true mn2 iff mn2 != 0)
__global__ __launch_bounds__(256, 4) void k_main(const float* __restrict__ spec, unsigned* __restrict__ mm,
                                                 int* __restrict__ counts2) {
    const int b = blockIdx.z;
    const int f0 = blockIdx.y * TF;
    const int t0 = blockIdx.x * TT;
    const int c0 = blockIdx.x;
    const int tid = threadIdx.x;

    __shared__ __align__(16) float sR1[R1_WORDS];
    __shared__ __align__(16) float sR2[R2_WORDS];
    const float4* sB4 = (const float4*)sR2;

    const float mn = decf(mm[b * 4 + 0]);
    const float mx = decf(mm[b * 4 + 1]);
    const float rinv = 1.0f / (mx - mn);
    const float* sb_base = spec + (size_t)b * NF * NT;

    const bool interior = (blockIdx.y >= 1 && blockIdx.y <= 14 && blockIdx.x >= 1 && blockIdx.x <= 30);
    if (interior) blur_tile_fast(sb_base, f0, t0, mn, rinv, sR1, sR2, tid);
    else          blur_tile_slow(sb_base, f0, t0, mn, rinv, sR1, sR2, tid);

    const int r = tid >> 4, m = tid & 15;
    Win8 w;
    load_win8(sB4, r, m, w);
    int cnt = 0;
    float lmin = __builtin_inff(), lmax = -__builtin_inff();
#pragma unroll
    for (int k = 0; k < 8; k++) {
        float x = w.c[k];
        lmin = fminf(lmin, x);
        lmax = fmaxf(lmax, x);
        bool pk = (x >= w.l[k]) && (x >= w.rr[k]) && (x >= w.u[k]) && (x >= w.d[k]);
        cnt += (pk && (x > 0.0f)) ? 1 : 0;
    }
    int cs = cnt;
    cs += __shfl_down(cs, 8, 16);
    cs += __shfl_down(cs, 4, 16);
    cs += __shfl_down(cs, 2, 16);
    cs += __shfl_down(cs, 1, 16);
    if (m == 0) counts2[(b * NF + f0 + r) * 32 + c0] = cs;

    for (int off = 32; off; off >>= 1) {
        lmin = fminf(lmin, __shfl_down(lmin, off));
        lmax = fmaxf(lmax, __shfl_down(lmax, off));
    }
    __shared__ float rmn[4], rmx[4];
    int wave = tid >> 6, lane = tid & 63;
    if (lane == 0) { rmn[wave] = lmin; rmx[wave] = lmax; }
    __syncthreads();
    if (tid == 0) {
        for (int w2 = 1; w2 < 4; w2++) { lmin = fminf(lmin, rmn[w2]); lmax = fmaxf(lmax, rmx[w2]); }
        atomicMin(&mm[b * 4 + 2], encf(lmin));
        atomicMax(&mm[b * 4 + 3], encf(lmax));
    }
}

// Guard pass: only does work if mn2 != 0; recounts with threshold x > mn2.
__global__ __launch_bounds__(256, 4) void k_fallback(const float* __restrict__ spec, unsigned* __restrict__ mm,
                                                     int* __restrict__ counts2) {
    const int b = blockIdx.z;
    const float mn2 = decf(mm[b * 4 + 2]);
    if (mn2 == 0.0f) return;

    const int f0 = blockIdx.y * TF;
    const int t0 = blockIdx.x * TT;
    const int c0 = blockIdx.x;
    const int tid = threadIdx.x;

    __shared__ __align__(16) float sR1[R1_WORDS];
    __shared__ __align__(16) float sR2[R2_WORDS];
    const float4* sB4 = (const float4*)sR2;

    const float mn = decf(mm[b * 4 + 0]);
    const float mx = decf(mm[b * 4 + 1]);
    const float rinv = 1.0f / (mx - mn);
    const float* sb_base = spec + (size_t)b * NF * NT;

    blur_tile_slow(sb_base, f0, t0, mn, rinv, sR1, sR2, tid);

    const int r = tid >> 4, m = tid & 15;
    Win8 w;
    load_win8(sB4, r, m, w);
    int cnt = 0;
#pragma unroll
    for (int k = 0; k < 8; k++) {
        float x = w.c[k];
        bool pk = (x >= w.l[k]) && (x >= w.rr[k]) && (x >= w.u[k]) && (x >= w.d[k]);
        cnt += (pk && (x > mn2)) ? 1 : 0;
    }
    cnt += __shfl_down(cnt, 8, 16);
    cnt += __shfl_down(cnt, 4, 16);
    cnt += __shfl_down(cnt, 2, 16);
    cnt += __shfl_down(cnt, 1, 16);
    if (m == 0) counts2[(b * NF + f0 + r) * 32 + c0] = cnt;
}

__global__ __launch_bounds__(256) void k_prefix(const int* __restrict__ counts2, int* __restrict__ prefix2) {
    const int b = blockIdx.x;
    const int tid = threadIdx.x;  // tid == freq row
    const int* cb = counts2 + b * NF * 32;
    int* pb = prefix2 + b * NF * 32;
    int local[32];
    int s = 0;
    for (int c = 0; c < 32; c++) {
        local[c] = cb[tid * 32 + c];
        s += local[c];
    }
    __shared__ int tot[256];
    tot[tid] = s;
    __syncthreads();
    for (int off = 1; off < 256; off <<= 1) {
        int v = (tid >= off) ? tot[tid - off] : 0;
        __syncthreads();
        tot[tid] += v;
        __syncthreads();
    }
    int run = tot[tid] - s;
    for (int c = 0; c < 32; c++) {
        pb[tid * 32 + c] = run;
        run += local[c];
    }
}

__global__ __launch_bounds__(256, 4) void k_extract(const float* __restrict__ spec, unsigned* __restrict__ mm,
                                                    const int* __restrict__ prefix2, float* __restrict__ out) {
    const int b = blockIdx.z;
    const int f0 = blockIdx.y * TF;
    const int t0 = blockIdx.x * TT;
    const int c0 = blockIdx.x;
    // prefix is monotone in row-major (f,chunk) order; tile min is at (f0,c0)
    if (prefix2[(b * NF + f0) * 32 + c0] >= PAD_LEN) return;

    const int tid = threadIdx.x;
    __shared__ __align__(16) float sR1[R1_WORDS];
    __shared__ __align__(16) float sR2[R2_WORDS];
    const float4* sB4 = (const float4*)sR2;

    const float mn = decf(mm[b * 4 + 0]);
    const float mx = decf(mm[b * 4 + 1]);
    const float rinv = 1.0f / (mx - mn);
    const float mn2 = decf(mm[b * 4 + 2]);
    const float mx2 = decf(mm[b * 4 + 3]);
    const float rinv2 = 1.0f / (mx2 - mn2);
    const float* sb_base = spec + (size_t)b * NF * NT;

    const bool interior = (blockIdx.y >= 1 && blockIdx.y <= 14 && blockIdx.x >= 1 && blockIdx.x <= 30);
    if (interior) blur_tile_fast(sb_base, f0, t0, mn, rinv, sR1, sR2, tid);
    else          blur_tile_slow(sb_base, f0, t0, mn, rinv, sR1, sR2, tid);

    const int r = tid >> 4, m = tid & 15;
    const int gf = f0 + r;
    const int base = prefix2[(b * NF + gf) * 32 + c0];
    Win8 w;
    load_win8(sB4, r, m, w);
    bool pos[8];
    int mycnt = 0;
#pragma unroll
    for (int k = 0; k < 8; k++) {
        float x = w.c[k];
        pos[k] = (x >= w.l[k]) && (x >= w.rr[k]) && (x >= w.u[k]) && (x >= w.d[k]) && (x > mn2);
        mycnt += pos[k] ? 1 : 0;
    }
    int scan = mycnt;
    for (int off = 1; off < 16; off <<= 1) {
        int v = __shfl_up(scan, off, 16);
        if (m >= off) scan += v;
    }
    int rank = base + (scan - mycnt);
#pragma unroll
    for (int k = 0; k < 8; k++) {
        if (pos[k]) {
            if (rank < PAD_LEN) {
                int gc = t0 + 8 * m + k;
                out[b * 768 + rank]       = (float)gf * (1.0f / 256.0f);
                out[b * 768 + 256 + rank] = (float)gc * (1.0f / 4096.0f);
                out[b * 768 + 512 + rank] = (w.c[k] - mn2) * rinv2;
            }
            rank++;
        }
    }
}

extern "C" void kernel_launch(void* const* d_in, const int* in_sizes, int n_in,
                              void* d_out, int out_size, void* d_ws, size_t ws_size,
                              hipStream_t stream) {
    const float* spec = (const float*)d_in[0];
    float* out = (float*)d_out;
    unsigned* mm = (unsigned*)((char*)d_ws + MM_OFF);
    int* counts2 = (int*)((char*)d_ws + CNT_OFF);
    int* prefix2 = (int*)((char*)d_ws + PFX_OFF);

    k_init<<<96, 256, 0, stream>>>(out, mm);
    k_minmax<<<dim3(64, NB), 256, 0, stream>>>(spec, mm);
    dim3 tgrid(NT / TT, NF / TF, NB);
    k_main<<<tgrid, 256, 0, stream>>>(spec, mm, counts2);
    k_fallback<<<tgrid, 256, 0, stream>>>(spec, mm, counts2);
    k_prefix<<<NB, 256, 0, stream>>>(counts2, prefix2);
    k_extract<<<tgrid, 256, 0, stream>>>(spec, mm, prefix2, out);
}